// Round 13
// baseline (532.446 us; speedup 1.0000x reference)
//
#include <hip/hip_runtime.h>
#include <math.h>

#define Bq 8
#define Tq 2048
#define Dq 1024
#define Mq (Bq*Tq)          // 16384 rows
#define NCHq 32             // chunks per channel
#define CHUNKq 64           // timesteps per chunk
#define DECAYq 0.99f
#define DF64q 0.52559646f   // 0.99^64
#define SGq (Bq*NCHq*4)     // scan blocks per direction = 1024
#define CEBNDq ((size_t)Bq*NCHq*Dq)  // chunk-end elems per direction

typedef unsigned short u16;
typedef unsigned int u32;
typedef __attribute__((ext_vector_type(8))) short bf16x8;
typedef __attribute__((ext_vector_type(4))) float f32x4;
typedef __attribute__((ext_vector_type(4))) u16 u16x4;

__device__ __forceinline__ u16 f2bf(float f) {
  u32 u = __builtin_bit_cast(u32, f);
  return (u16)((u + 0x7FFFu + ((u >> 16) & 1u)) >> 16);
}
__device__ __forceinline__ float bf2f(u16 h) {
  return __builtin_bit_cast(float, (u32)h << 16);
}
__device__ __forceinline__ float sigm(float x) { return 1.0f / (1.0f + expf(-x)); }

// ---------------- merged weight prep: 5 transposes in ONE dispatch --------
__global__ __launch_bounds__(256)
void transpose_all(const float* __restrict__ s0, u16* __restrict__ d0,
                   const float* __restrict__ s1, u16* __restrict__ d1,
                   const float* __restrict__ s2, u16* __restrict__ d2,
                   const float* __restrict__ s3, u16* __restrict__ d3,
                   const float* __restrict__ s4, u16* __restrict__ d4) {
  const int bid = blockIdx.x;
  const float* src; u16* dst; int K, N, local;
  if (bid < 1024)      { src = s0; dst = d0; K = 1024; N = 1024; local = bid; }
  else if (bid < 2048) { src = s1; dst = d1; K = 1024; N = 1024; local = bid - 1024; }
  else if (bid < 4096) { src = s2; dst = d2; K = 2048; N = 1024; local = bid - 2048; }
  else if (bid < 6144) { src = s3; dst = d3; K = 1024; N = 2048; local = bid - 4096; }
  else                 { src = s4; dst = d4; K = 2048; N = 1024; local = bid - 6144; }
  const int ntx = N >> 5;
  const int n0 = (local % ntx) << 5;
  const int k0 = (local / ntx) << 5;
  __shared__ float tile[32][33];
  const int tx = threadIdx.x & 31;
  const int ty = threadIdx.x >> 5;   // 0..7
#pragma unroll
  for (int j = 0; j < 32; j += 8)
    tile[ty + j][tx] = src[(size_t)(k0 + ty + j) * N + (n0 + tx)];
  __syncthreads();
#pragma unroll
  for (int j = 0; j < 32; j += 8)
    dst[(size_t)(n0 + ty + j) * K + (k0 + tx)] = f2bf(tile[tx][ty + j]);
}

// ---------------- LayerNorm (fp32 input): one row per 256-thread block ----
__global__ __launch_bounds__(256)
void ln_kernel(const float* __restrict__ xin, const float* __restrict__ w,
               const float* __restrict__ bb, u16* __restrict__ obf) {
  const int row = blockIdx.x;
  const int tid = threadIdx.x;
  const float4 v = ((const float4*)(xin + (size_t)row * Dq))[tid];
  float s  = v.x + v.y + v.z + v.w;
  float s2 = v.x*v.x + v.y*v.y + v.z*v.z + v.w*v.w;
#pragma unroll
  for (int o = 32; o > 0; o >>= 1) { s += __shfl_xor(s, o); s2 += __shfl_xor(s2, o); }
  __shared__ float rs[4], rq[4];
  const int wid = tid >> 6;
  if ((tid & 63) == 0) { rs[wid] = s; rq[wid] = s2; }
  __syncthreads();
  s  = rs[0] + rs[1] + rs[2] + rs[3];
  s2 = rq[0] + rq[1] + rq[2] + rq[3];
  const float mu  = s * (1.0f/Dq);
  const float var = s2 * (1.0f/Dq) - mu*mu;
  const float inv = rsqrtf(var + 1e-5f);
  const float4 wv = ((const float4*)w)[tid];
  const float4 bv = ((const float4*)bb)[tid];
  float4 o;
  o.x = (v.x - mu)*inv*wv.x + bv.x;
  o.y = (v.y - mu)*inv*wv.y + bv.y;
  o.z = (v.z - mu)*inv*wv.z + bv.z;
  o.w = (v.w - mu)*inv*wv.w + bv.w;
  u16x4 ob; ob[0] = f2bf(o.x); ob[1] = f2bf(o.y); ob[2] = f2bf(o.z); ob[3] = f2bf(o.w);
  ((u16x4*)(obf + (size_t)row * Dq))[tid] = ob;
}

// ---------------- LayerNorm (bf16 input): one row per 256-thread block ----
__global__ __launch_bounds__(256)
void ln_bf_kernel(const u16* __restrict__ xin, const float* __restrict__ w,
                  const float* __restrict__ bb, u16* __restrict__ obf) {
  const int row = blockIdx.x;
  const int tid = threadIdx.x;
  const u16x4 vu = ((const u16x4*)(xin + (size_t)row * Dq))[tid];
  float v0 = bf2f(vu[0]), v1 = bf2f(vu[1]), v2 = bf2f(vu[2]), v3 = bf2f(vu[3]);
  float s  = v0 + v1 + v2 + v3;
  float s2 = v0*v0 + v1*v1 + v2*v2 + v3*v3;
#pragma unroll
  for (int o = 32; o > 0; o >>= 1) { s += __shfl_xor(s, o); s2 += __shfl_xor(s2, o); }
  __shared__ float rs[4], rq[4];
  const int wid = tid >> 6;
  if ((tid & 63) == 0) { rs[wid] = s; rq[wid] = s2; }
  __syncthreads();
  s  = rs[0] + rs[1] + rs[2] + rs[3];
  s2 = rq[0] + rq[1] + rq[2] + rq[3];
  const float mu  = s * (1.0f/Dq);
  const float var = s2 * (1.0f/Dq) - mu*mu;
  const float inv = rsqrtf(var + 1e-5f);
  const float4 wv = ((const float4*)w)[tid];
  const float4 bv = ((const float4*)bb)[tid];
  u16x4 ob;
  ob[0] = f2bf((v0 - mu)*inv*wv.x + bv.x);
  ob[1] = f2bf((v1 - mu)*inv*wv.y + bv.y);
  ob[2] = f2bf((v2 - mu)*inv*wv.z + bv.z);
  ob[3] = f2bf((v3 - mu)*inv*wv.w + bv.w);
  ((u16x4*)(obf + (size_t)row * Dq))[tid] = ob;
}

// ---------------- dual-direction chunked decay scan (bf16, fp32 accum) ----
__global__ __launch_bounds__(256)
void scan_pass1_dual(const u16* __restrict__ vf, const u16* __restrict__ vb,
                     float* __restrict__ ce) {
  int bid = blockIdx.x;
  const bool rev = bid >= SGq;
  if (rev) bid -= SGq;
  const int dblk = bid & 3;
  const int c    = (bid >> 2) & 31;
  const int b    = bid >> 7;
  const int d    = (dblk << 8) + threadIdx.x;
  const u16* v   = rev ? vb : vf;
  float* cep     = ce + (rev ? CEBNDq : 0);
  const long step = rev ? -(long)Dq : (long)Dq;
  size_t idx = ((size_t)b * Tq + (rev ? (Tq - 1 - c * CHUNKq) : c * CHUNKq)) * Dq + d;
  float e = 0.0f;
  for (int i = 0; i < CHUNKq; ++i) { e = DECAYq * e + bf2f(v[idx]); idx += step; }
  cep[((size_t)b * NCHq + c) * Dq + d] = e;
}

__global__ __launch_bounds__(256)
void scan_pass2_dual(const float* __restrict__ ce, float* __restrict__ car) {
  const int idx = blockIdx.x * 256 + threadIdx.x;  // 0..16383 -> (dir,b,d)
  const int dir = idx >> 13;
  const int loc = idx & 8191;
  const int b = loc >> 10;
  const int d = loc & 1023;
  const size_t base = (size_t)dir * CEBNDq;
  float c = 0.0f;
  for (int k = 0; k < NCHq; ++k) {
    const size_t i = base + ((size_t)b * NCHq + k) * Dq + d;
    car[i] = c;
    c = DF64q * c + ce[i];
  }
}

__global__ __launch_bounds__(256)
void scan_pass3_dual(u16* __restrict__ vf, u16* __restrict__ vb,
                     const float* __restrict__ car) {
  int bid = blockIdx.x;
  const bool rev = bid >= SGq;
  if (rev) bid -= SGq;
  const int dblk = bid & 3;
  const int c    = (bid >> 2) & 31;
  const int b    = bid >> 7;
  const int d    = (dblk << 8) + threadIdx.x;
  u16* v = rev ? vb : vf;
  const float* carp = car + (rev ? CEBNDq : 0);
  float hc = carp[((size_t)b * NCHq + c) * Dq + d];
  const long step = rev ? -(long)Dq : (long)Dq;
  size_t idx = ((size_t)b * Tq + (rev ? (Tq - 1 - c * CHUNKq) : c * CHUNKq)) * Dq + d;
  for (int i = 0; i < CHUNKq; ++i) {
    hc = DECAYq * hc + bf2f(v[idx]);
    v[idx] = f2bf(hc);
    idx += step;
  }
}

// ---------------- fused epilogues ----------------
struct EpiGate {   // merged fwd|bwd gate: c<1024 -> fwd, else bwd
  const u16* h; const float* mask; const float* bgf; const float* bgb;
  u16* vf; u16* vb;
  __device__ void operator()(int r, int c, float val) const {
    const bool fwd = c < 1024;
    const int cc = c & 1023;
    const float s = sigm(val + (fwd ? bgf[cc] : bgb[cc]));
    const float hv = bf2f(h[(size_t)r * Dq + cc]) * mask[r];
    (fwd ? vf : vb)[(size_t)r * Dq + cc] = f2bf(s * hv);
  }
};
struct EpiFuse {   // beta-blend + residual -> x2 (bf16)
  const float* bfuse; const float* x; const u16* hf; const u16* hb; u16* x2;
  __device__ void operator()(int r, int c, float val) const {
    const size_t i = (size_t)r * Dq + c;
    const float bta = sigm(val + bfuse[c]);
    x2[i] = f2bf(x[i] + bta * bf2f(hf[i]) + (1.0f - bta) * bf2f(hb[i]));
  }
};
struct EpiFfn1 {
  const float* b1; u16* a;
  __device__ void operator()(int r, int c, float val) const {
    const float u = val + b1[c];
    const float g = 0.5f * u * (1.0f + erff(u * 0.70710678118f));
    a[(size_t)r * 2048 + c] = f2bf(g);
  }
};
struct EpiFfn2 {   // + bias + residual (bf16 x2) -> fp32 out
  const float* b2; const u16* x2; float* o;
  __device__ void operator()(int r, int c, float val) const {
    const size_t i = (size_t)r * Dq + c;
    o[i] = val + b2[c] + bf2f(x2[i]);
  }
};

// ---------------- bf16 MFMA GEMM: C = A(MxK) * BT(NxK)^T, 128x128 tile ----
// r10 structure with BK=32 + PAIRED-ROW LDS layout -> 32 KiB LDS ->
// 4 blocks/CU = 32 waves/CU (max occupancy; r10 was LDS-capped at 2 blocks).
// Paired-row layout: physical LDS row p (128B) holds logical rows 2p (bytes
// 0-63) and 2p+1 (bytes 64-127), preserving the 8-slot XOR swizzle
// (slot' = slot ^ (p&7)). Bank check (16-lane group, fixed k-group g):
// bank-quad = ((r&1)*4+g) ^ (r>>1) covers all 8 quads exactly 2x -> 2-way =
// free (m136). Source pre-swizzle composes with read swizzle to identity.
// Sync discipline = r10 verbatim: stage(t+1) at loop top -> compute(t)
// -> sched_barrier(0) -> s_waitcnt vmcnt(0) lgkmcnt(0) -> s_barrier.
// __launch_bounds__(512,8) pins VGPR <= 64 so 32 waves/CU is attainable.
template<typename Epi>
__global__ __launch_bounds__(512, 8)
void gemm_bt(const u16* __restrict__ A, const u16* __restrict__ A2, int ksplit,
             const u16* __restrict__ BT, int K, int nx, Epi epi) {
  __shared__ u16 As[2][4096];   // [buf][64 prow x 128B] = 8 KiB/buf, paired-row
  __shared__ u16 Bs[2][4096];
  const int tid  = threadIdx.x;
  const int lane = tid & 63;
  const int w    = tid >> 6;    // 0..7
  const int wr   = w >> 2;      // 0..1 (row half)
  const int wc   = w & 3;       // 0..3 (col quarter)

  // XCD-aware bijective remap, col-panel fastest within an XCD chunk.
  const int lin = blockIdx.x;
  const int q8  = gridDim.x >> 3;
  const int t   = (lin & 7) * q8 + (lin >> 3);
  const int by  = t / nx;
  const int bx  = t - by * nx;
  const int rowBase = by << 7;
  const int colBase = bx << 7;

  // paired-row staging: thread tid writes phys bytes [tid*16, tid*16+16).
  // phys row p = tid>>3; swizzled slot sp = (tid&7)^(p&7); that slot holds
  // logical row lr = 2p + (sp>>2), elem col ce = (sp&3)*8 of the K-tile.
  const int p_  = tid >> 3;                 // 0..63
  const int sp  = (tid & 7) ^ (p_ & 7);     // 0..7
  const int lr  = (p_ << 1) + (sp >> 2);    // 0..127
  const int ce_ = (sp & 3) << 3;            // 0,8,16,24 (elems)
  const int KA  = (ksplit < K) ? ksplit : K;

  auto stage = [&](int buf, int kt) {
    const int kbase = kt << 5;
    const u16* Abase = (kbase < ksplit) ? A : A2;
    const int  kA    = (kbase < ksplit) ? kbase : (kbase - ksplit);
    const u16* ga = Abase + (size_t)(rowBase + lr) * KA + kA + ce_;
    const u16* gb = BT    + (size_t)(colBase + lr) * K + kbase + ce_;
    __builtin_amdgcn_global_load_lds(
        (const __attribute__((address_space(1))) void*)ga,
        (__attribute__((address_space(3))) void*)((char*)&As[buf][0] + (tid << 4)), 16, 0, 0);
    __builtin_amdgcn_global_load_lds(
        (const __attribute__((address_space(1))) void*)gb,
        (__attribute__((address_space(3))) void*)((char*)&Bs[buf][0] + (tid << 4)), 16, 0, 0);
  };

  f32x4 acc[4][2];
#pragma unroll
  for (int m = 0; m < 4; ++m)
#pragma unroll
    for (int n = 0; n < 2; ++n) acc[m][n] = (f32x4){0.f, 0.f, 0.f, 0.f};

  const int nkt = K >> 5;     // 32 or 64 K-steps
  stage(0, 0);
  asm volatile("s_waitcnt vmcnt(0)" ::: "memory");
  __builtin_amdgcn_s_barrier();          // tile 0 resident, all waves see it

  const int g16 = (lane >> 4) << 4;      // byte col of k-group in 64B logical row
  int cur = 0;
  for (int kt = 0; kt < nkt; ++kt) {
    if (kt + 1 < nkt) stage(cur ^ 1, kt + 1);   // issue next tile BEFORE compute
    const char* Ab = (const char*)&As[cur][0];
    const char* Bb = (const char*)&Bs[cur][0];
    bf16x8 af[4], bfr[2];
#pragma unroll
    for (int m = 0; m < 4; ++m) {
      const int r  = (wr << 6) + (m << 4) + (lane & 15);
      const int pr = r >> 1;
      const int c  = (((r & 1) << 6) + g16) ^ ((pr & 7) << 4);
      af[m] = *(const bf16x8*)(Ab + (pr << 7) + c);
    }
#pragma unroll
    for (int n = 0; n < 2; ++n) {
      const int r  = (wc << 5) + (n << 4) + (lane & 15);
      const int pr = r >> 1;
      const int c  = (((r & 1) << 6) + g16) ^ ((pr & 7) << 4);
      bfr[n] = *(const bf16x8*)(Bb + (pr << 7) + c);
    }
#pragma unroll
    for (int m = 0; m < 4; ++m)
#pragma unroll
      for (int n = 0; n < 2; ++n)
        acc[m][n] = __builtin_amdgcn_mfma_f32_16x16x32_bf16(af[m], bfr[n], acc[m][n], 0, 0, 0);
    // Pin compute above; drain THIS wave's DMA before the barrier so all
    // waves' DMA is visible after it (round-4/5 race discipline).
    __builtin_amdgcn_sched_barrier(0);
    asm volatile("s_waitcnt vmcnt(0) lgkmcnt(0)" ::: "memory");
    __builtin_amdgcn_s_barrier();
    cur ^= 1;
  }

  // epilogue: C/D layout col = lane&15, row = (lane>>4)*4 + reg
#pragma unroll
  for (int m = 0; m < 4; ++m) {
    const int grow0 = rowBase + (wr << 6) + (m << 4) + ((lane >> 4) << 2);
#pragma unroll
    for (int n = 0; n < 2; ++n) {
      const int gcol = colBase + (wc << 5) + (n << 4) + (lane & 15);
#pragma unroll
      for (int r2 = 0; r2 < 4; ++r2)
        epi(grow0 + r2, gcol, acc[m][n][r2]);
    }
  }
}

// ---------------- launcher ----------------
extern "C" void kernel_launch(void* const* d_in, const int* in_sizes, int n_in,
                              void* d_out, int out_size, void* d_ws, size_t ws_size,
                              hipStream_t stream) {
  (void)in_sizes; (void)n_in; (void)out_size; (void)ws_size;
  const float* x      = (const float*)d_in[0];
  const float* mask   = (const float*)d_in[1];
  const float* ln1w   = (const float*)d_in[2];
  const float* ln1b   = (const float*)d_in[3];
  const float* ln2w   = (const float*)d_in[4];
  const float* ln2b   = (const float*)d_in[5];
  const float* Wg_f   = (const float*)d_in[6];
  const float* bg_f   = (const float*)d_in[7];
  const float* Wg_b   = (const float*)d_in[8];
  const float* bg_b   = (const float*)d_in[9];
  const float* W_fuse = (const float*)d_in[10];
  const float* b_fuse = (const float*)d_in[11];
  const float* W_ffn1 = (const float*)d_in[12];
  const float* b_ffn1 = (const float*)d_in[13];
  const float* W_ffn2 = (const float*)d_in[14];
  const float* b_ffn2 = (const float*)d_in[15];
  float* out = (float*)d_out;

  // ---- workspace layout: ~148 MiB total ----
  char* ws = (char*)d_ws;
  size_t off = 0;
  auto alloc = [&](size_t bytes) { char* p = ws + off; off += (bytes + 255) & ~(size_t)255; return p; };
  u16*   x2     = (u16*)  alloc((size_t)Mq * Dq * 2);      // 32 MiB bf16 residual, steps 7-10
  u16*   slotA  = (u16*)  alloc((size_t)Mq * Dq * 2);      // 32 MiB: h_bf16 -> y2
  u16*   hf_bf  = (u16*)  alloc((size_t)Mq * Dq * 2);      // 32 MiB: v_fwd -> h_fwd -> a lo
  u16*   hb_bf  = (u16*)  alloc((size_t)Mq * Dq * 2);      // 32 MiB: v_bwd -> h_bwd -> a hi
  u16*   WgT    = (u16*)  alloc((size_t)2048 * 1024 * 2);  // 4 MiB [2048][1024] (fwd|bwd rows)
  u16*   WfuT   = (u16*)  alloc((size_t)1024 * 2048 * 2);  // 4 MiB [1024][2048]
  u16*   Wf1T   = (u16*)  alloc((size_t)2048 * 1024 * 2);  // 4 MiB [2048][1024]
  u16*   Wf2T   = (u16*)  alloc((size_t)1024 * 2048 * 2);  // 4 MiB [1024][2048]
  float* ce     = (float*)alloc(2 * CEBNDq * 4);           // 2 MiB (fwd|bwd halves)
  float* car    = (float*)alloc(2 * CEBNDq * 4);           // 2 MiB
  u16*   h_bf16 = slotA;
  u16*   y2     = slotA;
  u16*   a_bf16 = hf_bf;   // hf|hb contiguous 64 MiB -> [M][2048] FFN1 activations

  // 1. merged weight prep (5 transposes, one dispatch)
  transpose_all<<<8192, 256, 0, stream>>>(Wg_f, WgT, Wg_b, WgT + 1024 * 1024,
                                          W_fuse, WfuT, W_ffn1, Wf1T, W_ffn2, Wf2T);

  // 2. LN1: x -> h_bf16
  ln_kernel<<<Mq, 256, 0, stream>>>(x, ln1w, ln1b, h_bf16);

  // 3. merged gate GEMM (N=2048 = fwd|bwd) -> v_fwd, v_bwd (bf16)
  EpiGate eg{h_bf16, mask, bg_f, bg_b, hf_bf, hb_bf};
  gemm_bt<EpiGate><<<16 * (Mq / 128), 512, 0, stream>>>(h_bf16, h_bf16, 1024, WgT, 1024, 16, eg);

  // 4. decay scans, both directions per dispatch, in-place bf16 v -> h
  scan_pass1_dual<<<2 * SGq, 256, 0, stream>>>(hf_bf, hb_bf, ce);
  scan_pass2_dual<<<64, 256, 0, stream>>>(ce, car);
  scan_pass3_dual<<<2 * SGq, 256, 0, stream>>>(hf_bf, hb_bf, car);

  // 7. fusion GEMM (K=2048, A split hf|hb), epilogue: beta-blend + residual -> x2 (bf16)
  EpiFuse ef{b_fuse, x, hf_bf, hb_bf, x2};
  gemm_bt<EpiFuse><<<8 * (Mq / 128), 512, 0, stream>>>(hf_bf, hb_bf, 1024, WfuT, 2048, 8, ef);

  // 8. LN2: x2 (bf16) -> y2
  ln_bf_kernel<<<Mq, 256, 0, stream>>>(x2, ln2w, ln2b, y2);

  // 9. FFN1 (N=2048) + exact GELU -> a_bf16
  EpiFfn1 e1{b_ffn1, a_bf16};
  gemm_bt<EpiFfn1><<<16 * (Mq / 128), 512, 0, stream>>>(y2, y2, 1024, Wf1T, 1024, 16, e1);

  // 10. FFN2 (K=2048) + bias + residual (bf16 x2) -> out
  EpiFfn2 e2{b_ffn2, x2, out};
  gemm_bt<EpiFfn2><<<8 * (Mq / 128), 512, 0, stream>>>(a_bf16, a_bf16, 2048, Wf2T, 2048, 8, e2);
}

// Round 14
// 498.841 us; speedup vs baseline: 1.0674x; 1.0674x over previous
//
#include <hip/hip_runtime.h>
#include <math.h>

#define Bq 8
#define Tq 2048
#define Dq 1024
#define Mq (Bq*Tq)          // 16384 rows
#define NCHq 32             // chunks per channel
#define CHUNKq 64           // timesteps per chunk
#define DECAYq 0.99f
#define DF64q 0.52559646f   // 0.99^64
#define SG2q (Bq*NCHq*2)    // paired-channel scan blocks per direction = 512
#define CEBNDq ((size_t)Bq*NCHq*Dq)  // chunk-end elems per direction

typedef unsigned short u16;
typedef unsigned int u32;
typedef __attribute__((ext_vector_type(8))) short bf16x8;
typedef __attribute__((ext_vector_type(4))) float f32x4;
typedef __attribute__((ext_vector_type(4))) u16 u16x4;

__device__ __forceinline__ u16 f2bf(float f) {
  u32 u = __builtin_bit_cast(u32, f);
  return (u16)((u + 0x7FFFu + ((u >> 16) & 1u)) >> 16);
}
__device__ __forceinline__ float bf2f(u16 h) {
  return __builtin_bit_cast(float, (u32)h << 16);
}
__device__ __forceinline__ float sigm(float x) { return 1.0f / (1.0f + expf(-x)); }

// ---------------- merged weight prep: 5 transposes in ONE dispatch --------
__global__ __launch_bounds__(256)
void transpose_all(const float* __restrict__ s0, u16* __restrict__ d0,
                   const float* __restrict__ s1, u16* __restrict__ d1,
                   const float* __restrict__ s2, u16* __restrict__ d2,
                   const float* __restrict__ s3, u16* __restrict__ d3,
                   const float* __restrict__ s4, u16* __restrict__ d4) {
  const int bid = blockIdx.x;
  const float* src; u16* dst; int K, N, local;
  if (bid < 1024)      { src = s0; dst = d0; K = 1024; N = 1024; local = bid; }
  else if (bid < 2048) { src = s1; dst = d1; K = 1024; N = 1024; local = bid - 1024; }
  else if (bid < 4096) { src = s2; dst = d2; K = 2048; N = 1024; local = bid - 2048; }
  else if (bid < 6144) { src = s3; dst = d3; K = 1024; N = 2048; local = bid - 4096; }
  else                 { src = s4; dst = d4; K = 2048; N = 1024; local = bid - 6144; }
  const int ntx = N >> 5;
  const int n0 = (local % ntx) << 5;
  const int k0 = (local / ntx) << 5;
  __shared__ float tile[32][33];
  const int tx = threadIdx.x & 31;
  const int ty = threadIdx.x >> 5;   // 0..7
#pragma unroll
  for (int j = 0; j < 32; j += 8)
    tile[ty + j][tx] = src[(size_t)(k0 + ty + j) * N + (n0 + tx)];
  __syncthreads();
#pragma unroll
  for (int j = 0; j < 32; j += 8)
    dst[(size_t)(n0 + ty + j) * K + (k0 + tx)] = f2bf(tile[tx][ty + j]);
}

// ---------------- LayerNorm (fp32 input): one row per 256-thread block ----
__global__ __launch_bounds__(256)
void ln_kernel(const float* __restrict__ xin, const float* __restrict__ w,
               const float* __restrict__ bb, u16* __restrict__ obf) {
  const int row = blockIdx.x;
  const int tid = threadIdx.x;
  const float4 v = ((const float4*)(xin + (size_t)row * Dq))[tid];
  float s  = v.x + v.y + v.z + v.w;
  float s2 = v.x*v.x + v.y*v.y + v.z*v.z + v.w*v.w;
#pragma unroll
  for (int o = 32; o > 0; o >>= 1) { s += __shfl_xor(s, o); s2 += __shfl_xor(s2, o); }
  __shared__ float rs[4], rq[4];
  const int wid = tid >> 6;
  if ((tid & 63) == 0) { rs[wid] = s; rq[wid] = s2; }
  __syncthreads();
  s  = rs[0] + rs[1] + rs[2] + rs[3];
  s2 = rq[0] + rq[1] + rq[2] + rq[3];
  const float mu  = s * (1.0f/Dq);
  const float var = s2 * (1.0f/Dq) - mu*mu;
  const float inv = rsqrtf(var + 1e-5f);
  const float4 wv = ((const float4*)w)[tid];
  const float4 bv = ((const float4*)bb)[tid];
  float4 o;
  o.x = (v.x - mu)*inv*wv.x + bv.x;
  o.y = (v.y - mu)*inv*wv.y + bv.y;
  o.z = (v.z - mu)*inv*wv.z + bv.z;
  o.w = (v.w - mu)*inv*wv.w + bv.w;
  u16x4 ob; ob[0] = f2bf(o.x); ob[1] = f2bf(o.y); ob[2] = f2bf(o.z); ob[3] = f2bf(o.w);
  ((u16x4*)(obf + (size_t)row * Dq))[tid] = ob;
}

// ---------------- LayerNorm (bf16 input): one row per 256-thread block ----
__global__ __launch_bounds__(256)
void ln_bf_kernel(const u16* __restrict__ xin, const float* __restrict__ w,
                  const float* __restrict__ bb, u16* __restrict__ obf) {
  const int row = blockIdx.x;
  const int tid = threadIdx.x;
  const u16x4 vu = ((const u16x4*)(xin + (size_t)row * Dq))[tid];
  float v0 = bf2f(vu[0]), v1 = bf2f(vu[1]), v2 = bf2f(vu[2]), v3 = bf2f(vu[3]);
  float s  = v0 + v1 + v2 + v3;
  float s2 = v0*v0 + v1*v1 + v2*v2 + v3*v3;
#pragma unroll
  for (int o = 32; o > 0; o >>= 1) { s += __shfl_xor(s, o); s2 += __shfl_xor(s2, o); }
  __shared__ float rs[4], rq[4];
  const int wid = tid >> 6;
  if ((tid & 63) == 0) { rs[wid] = s; rq[wid] = s2; }
  __syncthreads();
  s  = rs[0] + rs[1] + rs[2] + rs[3];
  s2 = rq[0] + rq[1] + rq[2] + rq[3];
  const float mu  = s * (1.0f/Dq);
  const float var = s2 * (1.0f/Dq) - mu*mu;
  const float inv = rsqrtf(var + 1e-5f);
  const float4 wv = ((const float4*)w)[tid];
  const float4 bv = ((const float4*)bb)[tid];
  u16x4 ob;
  ob[0] = f2bf((v0 - mu)*inv*wv.x + bv.x);
  ob[1] = f2bf((v1 - mu)*inv*wv.y + bv.y);
  ob[2] = f2bf((v2 - mu)*inv*wv.z + bv.z);
  ob[3] = f2bf((v3 - mu)*inv*wv.w + bv.w);
  ((u16x4*)(obf + (size_t)row * Dq))[tid] = ob;
}

// ------ dual-direction chunked decay scan, PAIRED-CHANNEL (u32 = 2 bf16) --
// 4 B/lane coalescing instead of 2 B/lane. blocks [0,SG2) = fwd, rest bwd.
__global__ __launch_bounds__(256)
void scan_pass1_dual(const u32* __restrict__ vf, const u32* __restrict__ vb,
                     float* __restrict__ ce) {
  int bid = blockIdx.x;
  const bool rev = bid >= SG2q;
  if (rev) bid -= SG2q;
  const int dp = ((bid & 1) << 8) + threadIdx.x;   // pair index 0..511
  const int c  = (bid >> 1) & 31;
  const int b  = bid >> 6;
  const u32* v = rev ? vb : vf;
  float* cep   = ce + (rev ? CEBNDq : 0);
  const long step = rev ? -(long)512 : (long)512;
  size_t idx = ((size_t)b * Tq + (rev ? (Tq - 1 - c * CHUNKq) : c * CHUNKq)) * 512 + dp;
  float e0 = 0.0f, e1 = 0.0f;
  for (int i = 0; i < CHUNKq; ++i) {
    const u32 pv = v[idx];
    e0 = DECAYq * e0 + bf2f((u16)(pv & 0xffffu));
    e1 = DECAYq * e1 + bf2f((u16)(pv >> 16));
    idx += step;
  }
  float2* o = (float2*)(cep + ((size_t)b * NCHq + c) * Dq + ((size_t)dp << 1));
  *o = make_float2(e0, e1);
}

__global__ __launch_bounds__(256)
void scan_pass2_dual(const float* __restrict__ ce, float* __restrict__ car) {
  const int idx = blockIdx.x * 256 + threadIdx.x;  // 0..16383 -> (dir,b,d)
  const int dir = idx >> 13;
  const int loc = idx & 8191;
  const int b = loc >> 10;
  const int d = loc & 1023;
  const size_t base = (size_t)dir * CEBNDq;
  float c = 0.0f;
  for (int k = 0; k < NCHq; ++k) {
    const size_t i = base + ((size_t)b * NCHq + k) * Dq + d;
    car[i] = c;
    c = DF64q * c + ce[i];
  }
}

// in-place: v (bf16 pairs) -> h (bf16 pairs), both directions in one dispatch
__global__ __launch_bounds__(256)
void scan_pass3_dual(u32* __restrict__ vf, u32* __restrict__ vb,
                     const float* __restrict__ car) {
  int bid = blockIdx.x;
  const bool rev = bid >= SG2q;
  if (rev) bid -= SG2q;
  const int dp = ((bid & 1) << 8) + threadIdx.x;
  const int c  = (bid >> 1) & 31;
  const int b  = bid >> 6;
  u32* v = rev ? vb : vf;
  const float* carp = car + (rev ? CEBNDq : 0);
  const float2 c2 = *(const float2*)(carp + ((size_t)b * NCHq + c) * Dq + ((size_t)dp << 1));
  float h0 = c2.x, h1 = c2.y;
  const long step = rev ? -(long)512 : (long)512;
  size_t idx = ((size_t)b * Tq + (rev ? (Tq - 1 - c * CHUNKq) : c * CHUNKq)) * 512 + dp;
  for (int i = 0; i < CHUNKq; ++i) {
    const u32 pv = v[idx];
    h0 = DECAYq * h0 + bf2f((u16)(pv & 0xffffu));
    h1 = DECAYq * h1 + bf2f((u16)(pv >> 16));
    v[idx] = (u32)f2bf(h0) | ((u32)f2bf(h1) << 16);
    idx += step;
  }
}

// ---------------- fused epilogues ----------------
struct EpiGate {   // merged fwd|bwd gate: c<1024 -> fwd, else bwd
  const u16* h; const float* mask; const float* bgf; const float* bgb;
  u16* vf; u16* vb;
  __device__ void operator()(int r, int c, float val) const {
    const bool fwd = c < 1024;
    const int cc = c & 1023;
    const float s = sigm(val + (fwd ? bgf[cc] : bgb[cc]));
    const float hv = bf2f(h[(size_t)r * Dq + cc]) * mask[r];
    (fwd ? vf : vb)[(size_t)r * Dq + cc] = f2bf(s * hv);
  }
};
struct EpiFuse {   // beta-blend + residual -> x2 (bf16)
  const float* bfuse; const float* x; const u16* hf; const u16* hb; u16* x2;
  __device__ void operator()(int r, int c, float val) const {
    const size_t i = (size_t)r * Dq + c;
    const float bta = sigm(val + bfuse[c]);
    x2[i] = f2bf(x[i] + bta * bf2f(hf[i]) + (1.0f - bta) * bf2f(hb[i]));
  }
};
struct EpiFfn1 {
  const float* b1; u16* a;
  __device__ void operator()(int r, int c, float val) const {
    const float u = val + b1[c];
    const float g = 0.5f * u * (1.0f + erff(u * 0.70710678118f));
    a[(size_t)r * 2048 + c] = f2bf(g);
  }
};
struct EpiFfn2 {   // + bias + residual (bf16 x2) -> fp32 out
  const float* b2; const u16* x2; float* o;
  __device__ void operator()(int r, int c, float val) const {
    const size_t i = (size_t)r * Dq + c;
    o[i] = val + b2[c] + bf2f(x2[i]);
  }
};

// ---------------- bf16 MFMA GEMM: C = A(MxK) * BT(NxK)^T, 128x128 tile ----
// ROUND-10/12 KERNEL, VERBATIM — FINAL. Session evidence: per-GEMM ~145 us
// is invariant across occupancy 22-76% (r13), five pipeline structures
// (r7 ring / r8 fine-phase / r9 m201-geom / r11 8-phase / r13 BK=32), and
// two tile sets. This is the 2-phase structure ceiling (learn_hip m230);
// all structured schedules lost more to barrier convoying than they gained.
// 512 threads / 8 waves (2M x 4N wave grid, 64x32 per-wave output).
// 1D grid with bijective XCD-chunk swizzle. 2-phase double-buffered LDS with
// EXPLICIT sync discipline: stage(t+1) at loop top -> compute(t)
// -> sched_barrier(0) -> s_waitcnt vmcnt(0) lgkmcnt(0) -> s_barrier.
template<typename Epi>
__global__ __launch_bounds__(512)
void gemm_bt(const u16* __restrict__ A, const u16* __restrict__ A2, int ksplit,
             const u16* __restrict__ BT, int K, int nx, Epi epi) {
  __shared__ u16 As[2][8192];   // [buf][128][64] bf16, XOR-swizzled rows
  __shared__ u16 Bs[2][8192];
  const int tid  = threadIdx.x;
  const int lane = tid & 63;
  const int w    = tid >> 6;    // 0..7
  const int wr   = w >> 2;      // 0..1 (row half)
  const int wc   = w & 3;       // 0..3 (col quarter)

  const int lin = blockIdx.x;
  const int q8  = gridDim.x >> 3;
  const int t   = (lin & 7) * q8 + (lin >> 3);
  const int by  = t / nx;
  const int bx  = t - by * nx;
  const int rowBase = by << 7;
  const int colBase = bx << 7;

  const int srow  = tid >> 3;                              // 0..63
  const int scolE = (((tid & 7) ^ (srow & 7)) << 4) >> 1;  // element col in source row
  const int KA    = (ksplit < K) ? ksplit : K;             // row stride of A buffers

  auto stage = [&](int buf, int kt) {
    const int kbase = kt << 6;
    const u16* Abase = (kbase < ksplit) ? A : A2;
    const int  kA    = (kbase < ksplit) ? kbase : (kbase - ksplit);
#pragma unroll
    for (int qq = 0; qq < 2; ++qq) {
      const u16* ga = Abase + (size_t)(rowBase + (qq << 6) + srow) * KA + kA + scolE;
      const u16* gb = BT    + (size_t)(colBase + (qq << 6) + srow) * K + kbase + scolE;
      __builtin_amdgcn_global_load_lds(
          (const __attribute__((address_space(1))) void*)ga,
          (__attribute__((address_space(3))) void*)(&As[buf][0] + (qq << 12) + (w << 9)), 16, 0, 0);
      __builtin_amdgcn_global_load_lds(
          (const __attribute__((address_space(1))) void*)gb,
          (__attribute__((address_space(3))) void*)(&Bs[buf][0] + (qq << 12) + (w << 9)), 16, 0, 0);
    }
  };

  f32x4 acc[4][2];
#pragma unroll
  for (int m = 0; m < 4; ++m)
#pragma unroll
    for (int n = 0; n < 2; ++n) acc[m][n] = (f32x4){0.f, 0.f, 0.f, 0.f};

  const int nkt = K >> 6;
  stage(0, 0);
  asm volatile("s_waitcnt vmcnt(0)" ::: "memory");
  __builtin_amdgcn_s_barrier();          // tile 0 resident, all waves see it

  int cur = 0;
  for (int kt = 0; kt < nkt; ++kt) {
    if (kt + 1 < nkt) stage(cur ^ 1, kt + 1);   // issue next tile BEFORE compute
    const char* Ab = (const char*)&As[cur][0];
    const char* Bb = (const char*)&Bs[cur][0];
#pragma unroll
    for (int kk = 0; kk < 2; ++kk) {
      bf16x8 af[4], bfr[2];
      const int cb = (kk << 6) + ((lane >> 4) << 4);   // byte col within 128B row
#pragma unroll
      for (int m = 0; m < 4; ++m) {
        const int r = (wr << 6) + (m << 4) + (lane & 15);
        af[m] = *(const bf16x8*)(Ab + (r << 7) + (cb ^ ((r & 7) << 4)));
      }
#pragma unroll
      for (int n = 0; n < 2; ++n) {
        const int r = (wc << 5) + (n << 4) + (lane & 15);
        bfr[n] = *(const bf16x8*)(Bb + (r << 7) + (cb ^ ((r & 7) << 4)));
      }
#pragma unroll
      for (int m = 0; m < 4; ++m)
#pragma unroll
        for (int n = 0; n < 2; ++n)
          acc[m][n] = __builtin_amdgcn_mfma_f32_16x16x32_bf16(af[m], bfr[n], acc[m][n], 0, 0, 0);
    }
    __builtin_amdgcn_sched_barrier(0);
    asm volatile("s_waitcnt vmcnt(0) lgkmcnt(0)" ::: "memory");
    __builtin_amdgcn_s_barrier();
    cur ^= 1;
  }

  // epilogue: C/D layout col = lane&15, row = (lane>>4)*4 + reg
#pragma unroll
  for (int m = 0; m < 4; ++m) {
    const int grow0 = rowBase + (wr << 6) + (m << 4) + ((lane >> 4) << 2);
#pragma unroll
    for (int n = 0; n < 2; ++n) {
      const int gcol = colBase + (wc << 5) + (n << 4) + (lane & 15);
#pragma unroll
      for (int r2 = 0; r2 < 4; ++r2)
        epi(grow0 + r2, gcol, acc[m][n][r2]);
    }
  }
}

// ---------------- launcher ----------------
extern "C" void kernel_launch(void* const* d_in, const int* in_sizes, int n_in,
                              void* d_out, int out_size, void* d_ws, size_t ws_size,
                              hipStream_t stream) {
  (void)in_sizes; (void)n_in; (void)out_size; (void)ws_size;
  const float* x      = (const float*)d_in[0];
  const float* mask   = (const float*)d_in[1];
  const float* ln1w   = (const float*)d_in[2];
  const float* ln1b   = (const float*)d_in[3];
  const float* ln2w   = (const float*)d_in[4];
  const float* ln2b   = (const float*)d_in[5];
  const float* Wg_f   = (const float*)d_in[6];
  const float* bg_f   = (const float*)d_in[7];
  const float* Wg_b   = (const float*)d_in[8];
  const float* bg_b   = (const float*)d_in[9];
  const float* W_fuse = (const float*)d_in[10];
  const float* b_fuse = (const float*)d_in[11];
  const float* W_ffn1 = (const float*)d_in[12];
  const float* b_ffn1 = (const float*)d_in[13];
  const float* W_ffn2 = (const float*)d_in[14];
  const float* b_ffn2 = (const float*)d_in[15];
  float* out = (float*)d_out;

  // ---- workspace layout: ~148 MiB total ----
  char* ws = (char*)d_ws;
  size_t off = 0;
  auto alloc = [&](size_t bytes) { char* p = ws + off; off += (bytes + 255) & ~(size_t)255; return p; };
  u16*   x2     = (u16*)  alloc((size_t)Mq * Dq * 2);      // 32 MiB bf16 residual, steps 7-10
  u16*   slotA  = (u16*)  alloc((size_t)Mq * Dq * 2);      // 32 MiB: h_bf16 -> y2
  u16*   hf_bf  = (u16*)  alloc((size_t)Mq * Dq * 2);      // 32 MiB: v_fwd -> h_fwd -> a lo
  u16*   hb_bf  = (u16*)  alloc((size_t)Mq * Dq * 2);      // 32 MiB: v_bwd -> h_bwd -> a hi
  u16*   WgT    = (u16*)  alloc((size_t)2048 * 1024 * 2);  // 4 MiB [2048][1024] (fwd|bwd rows)
  u16*   WfuT   = (u16*)  alloc((size_t)1024 * 2048 * 2);  // 4 MiB [1024][2048]
  u16*   Wf1T   = (u16*)  alloc((size_t)2048 * 1024 * 2);  // 4 MiB [2048][1024]
  u16*   Wf2T   = (u16*)  alloc((size_t)1024 * 2048 * 2);  // 4 MiB [1024][2048]
  float* ce     = (float*)alloc(2 * CEBNDq * 4);           // 2 MiB (fwd|bwd halves)
  float* car    = (float*)alloc(2 * CEBNDq * 4);           // 2 MiB
  u16*   h_bf16 = slotA;
  u16*   y2     = slotA;
  u16*   a_bf16 = hf_bf;   // hf|hb contiguous 64 MiB -> [M][2048] FFN1 activations

  // 1. merged weight prep (5 transposes, one dispatch)
  transpose_all<<<8192, 256, 0, stream>>>(Wg_f, WgT, Wg_b, WgT + 1024 * 1024,
                                          W_fuse, WfuT, W_ffn1, Wf1T, W_ffn2, Wf2T);

  // 2. LN1: x -> h_bf16
  ln_kernel<<<Mq, 256, 0, stream>>>(x, ln1w, ln1b, h_bf16);

  // 3. merged gate GEMM (N=2048 = fwd|bwd) -> v_fwd, v_bwd (bf16)
  EpiGate eg{h_bf16, mask, bg_f, bg_b, hf_bf, hb_bf};
  gemm_bt<EpiGate><<<16 * (Mq / 128), 512, 0, stream>>>(h_bf16, h_bf16, 1024, WgT, 1024, 16, eg);

  // 4. decay scans, both directions per dispatch, paired-channel u32 access
  scan_pass1_dual<<<2 * SG2q, 256, 0, stream>>>((const u32*)hf_bf, (const u32*)hb_bf, ce);
  scan_pass2_dual<<<64, 256, 0, stream>>>(ce, car);
  scan_pass3_dual<<<2 * SG2q, 256, 0, stream>>>((u32*)hf_bf, (u32*)hb_bf, car);

  // 7. fusion GEMM (K=2048, A split hf|hb), epilogue: beta-blend + residual -> x2 (bf16)
  EpiFuse ef{b_fuse, x, hf_bf, hb_bf, x2};
  gemm_bt<EpiFuse><<<8 * (Mq / 128), 512, 0, stream>>>(hf_bf, hb_bf, 1024, WfuT, 2048, 8, ef);

  // 8. LN2: x2 (bf16) -> y2
  ln_bf_kernel<<<Mq, 256, 0, stream>>>(x2, ln2w, ln2b, y2);

  // 9. FFN1 (N=2048) + exact GELU -> a_bf16
  EpiFfn1 e1{b_ffn1, a_bf16};
  gemm_bt<EpiFfn1><<<16 * (Mq / 128), 512, 0, stream>>>(y2, y2, 1024, Wf1T, 1024, 16, e1);

  // 10. FFN2 (K=2048) + bias + residual (bf16 x2) -> out
  EpiFfn2 e2{b_ffn2, x2, out};
  gemm_bt<EpiFfn2><<<8 * (Mq / 128), 512, 0, stream>>>(a_bf16, a_bf16, 2048, Wf2T, 2048, 8, e2);
}